// Round 2
// baseline (146.498 us; speedup 1.0000x reference)
//
#include <hip/hip_runtime.h>

#define NN 17    // nodes
#define D  512   // feature dim
#define H  8     // heads
#define C1 515   // D + 3
#define M  256   // hidden

#define NBLOCKS 128                          // = H*16 (phase-1 grid); <= 256 CUs -> all co-resident

#define XPAD 20                              // [d][n] row stride (17 + pad)
#define RSN  36                              // reduction row: 32 e + pad
#define RSG  (NN * RSN)                      // 612 floats per group
#define SMEM_FL (32 * RSG)                   // 19584 floats = 78.3 KB (union buffer)

__device__ __forceinline__ void fma4(float4& a, float x, const float4& w) {
    a.x = fmaf(x, w.x, a.x); a.y = fmaf(x, w.y, a.y);
    a.z = fmaf(x, w.z, a.z); a.w = fmaf(x, w.w, a.w);
}

// Manual grid barrier: all NBLOCKS blocks are co-resident by construction
// (128 blocks <= 256 CUs, 78.3KB LDS < 160KB, <=1 block/CU needed), so the
// spin cannot deadlock. Counter zeroed by hipMemsetAsync before each launch.
__device__ __forceinline__ void grid_barrier(unsigned int* ctr, unsigned int nb) {
    __threadfence();                 // release: drain this thread's global stores (L2 wb)
    __syncthreads();
    if (threadIdx.x == 0) {
        atomicAdd(ctr, 1u);          // device-scope by default on HIP
        while (__hip_atomic_load(ctr, __ATOMIC_RELAXED, __HIP_MEMORY_SCOPE_AGENT) < nb) {
            __builtin_amdgcn_s_sleep(8);
        }
    }
    __syncthreads();
    __threadfence();                 // acquire: invalidate stale cache before remote reads
}

// Single fused kernel: 128 blocks x 256 threads, 2 manual grid barriers.
// Phase 1 (all 128 blocks):  f[h,n,e] = relu(Xs @ FC[h])        (old k1)
// Phase 2 (blocks 0..63):    hdn[h,n,m] = tanh([f,ROI]@W1+b1)   (old k2)
// Phase 3 (blocks 0..16):    scores -> softmax -> weighted sum  (old k34)
__global__ __launch_bounds__(256) void fused_all(
        const float* __restrict__ Xs,     const float* __restrict__ ROIs,
        const float* __restrict__ FC,     const float* __restrict__ W1,
        const float* __restrict__ b1,     const float* __restrict__ W2,
        const float* __restrict__ b2,     const float* __restrict__ conv_w,
        const float* __restrict__ conv_b, float* __restrict__ out,
        float* __restrict__ f,            float* __restrict__ hdn,
        unsigned int* __restrict__ ctrs) {
    const int b = blockIdx.x;
    const int t = threadIdx.x;
    __shared__ __align__(16) float sm[SMEM_FL];

    // ---------------- Phase 1: f = relu(Xs @ FC[h]) ----------------
    {
        const int et = b & 15, h = b >> 4;
        const int tw = t & 7, cgr = t >> 3;
        for (int i = t; i < NN * D; i += 256) {
            const int n = i >> 9, d = i & 511;
            sm[d * XPAD + n] = Xs[i];
        }
        __syncthreads();
        float4 acc[NN];
#pragma unroll
        for (int n = 0; n < NN; ++n) acc[n] = make_float4(0.f, 0.f, 0.f, 0.f);
        const float4* fc4 = (const float4*)(FC + (size_t)h * D * D) + et * 8 + tw;
#pragma unroll 4
        for (int i = 0; i < 16; ++i) {
            const int d = cgr + (i << 5);
            const float4 w = fc4[d << 7];            // [d][512/4] row stride 128
            const float* xr = sm + d * XPAD;
#pragma unroll
            for (int n4 = 0; n4 < 4; ++n4) {
                const float4 x = *(const float4*)(xr + (n4 << 2));
                fma4(acc[n4 * 4 + 0], x.x, w);
                fma4(acc[n4 * 4 + 1], x.y, w);
                fma4(acc[n4 * 4 + 2], x.z, w);
                fma4(acc[n4 * 4 + 3], x.w, w);
            }
            fma4(acc[16], xr[16], w);
        }
        __syncthreads();                 // xs_t reads done; reuse smem for reduction
        float* rr = sm + cgr * RSG + tw * 4;
#pragma unroll
        for (int n = 0; n < NN; ++n) *(float4*)(rr + n * RSN) = acc[n];
        __syncthreads();
        for (int i = t; i < NN * 32; i += 256) {
            const int n = i >> 5, e = i & 31;
            float s = 0.f;
#pragma unroll 8
            for (int g = 0; g < 32; ++g) s += sm[g * RSG + n * RSN + e];
            f[((h * NN + n) << 9) + (et << 5) + e] = fmaxf(s, 0.f);
        }
    }
    grid_barrier(ctrs + 0, NBLOCKS);     // f visible to all blocks

    // ---------------- Phase 2: hdn = tanh([f,ROI] @ W1 + b1) ----------------
    if (b < H * 8) {
        const int mt = b & 7, h = b >> 3;
        const int tw = t & 7, cgr = t >> 3;
        for (int i = t; i < NN * D; i += 256) {
            const int n = i >> 9, d = i & 511;
            sm[d * XPAD + n] = f[((size_t)(h * NN) << 9) + i];
        }
        if (t < NN * 3) {
            const int n = t / 3, cc = t % 3;
            sm[(D + cc) * XPAD + n] = ROIs[t];
        }
        __syncthreads();
        float4 acc[NN];
#pragma unroll
        for (int n = 0; n < NN; ++n) acc[n] = make_float4(0.f, 0.f, 0.f, 0.f);
        const float4* w4 = (const float4*)(W1 + (size_t)h * C1 * M) + mt * 8 + tw;
#pragma unroll 4
        for (int i = 0; i < 16; ++i) {
            const int c = cgr + (i << 5);
            const float4 w = w4[c << 6];             // [c][256/4] row stride 64
            const float* xr = sm + c * XPAD;
#pragma unroll
            for (int n4 = 0; n4 < 4; ++n4) {
                const float4 x = *(const float4*)(xr + (n4 << 2));
                fma4(acc[n4 * 4 + 0], x.x, w);
                fma4(acc[n4 * 4 + 1], x.y, w);
                fma4(acc[n4 * 4 + 2], x.z, w);
                fma4(acc[n4 * 4 + 3], x.w, w);
            }
            fma4(acc[16], xr[16], w);
        }
        if (cgr < 3) {                               // tail rows c = 512..514 (ROI)
            const int c = D + cgr;
            const float4 w = w4[c << 6];
            const float* xr = sm + c * XPAD;
#pragma unroll
            for (int n4 = 0; n4 < 4; ++n4) {
                const float4 x = *(const float4*)(xr + (n4 << 2));
                fma4(acc[n4 * 4 + 0], x.x, w);
                fma4(acc[n4 * 4 + 1], x.y, w);
                fma4(acc[n4 * 4 + 2], x.z, w);
                fma4(acc[n4 * 4 + 3], x.w, w);
            }
            fma4(acc[16], xr[16], w);
        }
        __syncthreads();
        float* rr = sm + cgr * RSG + tw * 4;
#pragma unroll
        for (int n = 0; n < NN; ++n) *(float4*)(rr + n * RSN) = acc[n];
        __syncthreads();
        for (int i = t; i < NN * 32; i += 256) {
            const int n = i >> 5, m = i & 31;
            float s = b1[h * M + (mt << 5) + m];
#pragma unroll 8
            for (int g = 0; g < 32; ++g) s += sm[g * RSG + n * RSN + m];
            hdn[(h * NN + n) * M + (mt << 5) + m] = tanhf(s);
        }
    }
    grid_barrier(ctrs + 32, NBLOCKS);    // hdn visible to all blocks

    // ---------------- Phase 3: scores -> softmax -> output ----------------
    if (b < NN) {
        const int k = b;
        float* swk = sm;                        // [H][M+4], row stride 260 (16B-aligned)
        float* sa  = sm + H * (M + 4);          // [H][NN]
        float* cwv = sm + H * (M + 4) + H * NN; // [H]
        for (int i = t; i < H * M; i += 256) {
            const int h = i >> 8, m = i & 255;
            swk[h * (M + 4) + m] = W2[(size_t)(h * M + m) * NN + k];
        }
        if (t < H) cwv[t] = conv_w[t];
        __syncthreads();
        if (t < H * NN) {
            const int h = t / NN, n = t % NN;
            const float4* a4 = (const float4*)(hdn + (h * NN + n) * M);
            const float4* w4 = (const float4*)(swk + h * (M + 4));
            float acc = b2[h * NN + k];
#pragma unroll 8
            for (int m4 = 0; m4 < M / 4; ++m4) {
                const float4 av = a4[m4];
                const float4 wv = w4[m4];
                acc = fmaf(av.x, wv.x, acc); acc = fmaf(av.y, wv.y, acc);
                acc = fmaf(av.z, wv.z, acc); acc = fmaf(av.w, wv.w, acc);
            }
            sa[h * NN + n] = acc;
        }
        __syncthreads();
        if (t < H) {
            float mx = -1e30f;
#pragma unroll
            for (int n = 0; n < NN; ++n) mx = fmaxf(mx, sa[t * NN + n]);
            float e[NN];
            float s = 0.f;
#pragma unroll
            for (int n = 0; n < NN; ++n) { e[n] = __expf(sa[t * NN + n] - mx); s += e[n]; }
            const float inv = 1.f / s;
#pragma unroll
            for (int n = 0; n < NN; ++n) sa[t * NN + n] = e[n] * inv;
        }
        __syncthreads();
        const float cb = conv_b[0];
        float acc0 = 0.f, acc1 = 0.f;
        for (int h = 0; h < H; ++h) {
            float w0 = 0.f, w1 = 0.f;
#pragma unroll
            for (int n = 0; n < NN; ++n) {
                const float a = sa[h * NN + n];
                const float* fr = f + (size_t)((h * NN + n) << 9);
                w0 = fmaf(a, fr[t], w0);
                w1 = fmaf(a, fr[t + 256], w1);
            }
            acc0 = fmaf(cwv[h], w0, acc0);
            acc1 = fmaf(cwv[h], w1, acc1);
        }
        out[(k << 9) + t]       = fmaxf(acc0 + cb, 0.f) + Xs[(k << 9) + t];
        out[(k << 9) + t + 256] = fmaxf(acc1 + cb, 0.f) + Xs[(k << 9) + t + 256];
        if (k == 0 && t < NN * 3) out[NN * D + t] = ROIs[t];
    }
}

extern "C" void kernel_launch(void* const* d_in, const int* in_sizes, int n_in,
                              void* d_out, int out_size, void* d_ws, size_t ws_size,
                              hipStream_t stream) {
    const float* Xs     = (const float*)d_in[0];
    const float* ROIs   = (const float*)d_in[1];
    // d_in[2] = adj, unused
    const float* FC     = (const float*)d_in[3];
    const float* W1     = (const float*)d_in[4];
    const float* b1     = (const float*)d_in[5];
    const float* W2     = (const float*)d_in[6];
    const float* b2     = (const float*)d_in[7];
    const float* conv_w = (const float*)d_in[8];
    const float* conv_b = (const float*)d_in[9];
    float* outp = (float*)d_out;

    float* fbuf   = (float*)d_ws;              // H*NN*D = 69632 floats
    float* hdnbuf = fbuf + H * NN * D;         // H*NN*M = 34816 floats

    // Barrier counters: far from f/hdn, zeroed each launch (stream-ordered,
    // graph-capturable). Two counters, 128B apart.
    unsigned int* ctrs = (unsigned int*)((char*)d_ws + (1u << 20));
    hipMemsetAsync(ctrs, 0, 256, stream);

    fused_all<<<NBLOCKS, 256, 0, stream>>>(Xs, ROIs, FC, W1, b1, W2, b2,
                                           conv_w, conv_b, outp, fbuf, hdnbuf,
                                           ctrs);
}

// Round 3
// 114.780 us; speedup vs baseline: 1.2763x; 1.2763x over previous
//
#include <hip/hip_runtime.h>

#define NN 17    // nodes
#define D  512   // feature dim
#define H  8     // heads
#define C1 515   // D + 3
#define M  256   // hidden

#define NBLOCKS 128                          // = H*16 (phase-1 grid); <= 256 CUs -> all co-resident

#define XPAD 20                              // [d][n] row stride (17 + pad)
#define RSN  36                              // reduction row: 32 e + pad
#define RSG  (NN * RSN)                      // 612 floats per group
#define SMEM_FL (32 * RSG)                   // 19584 floats = 78.3 KB (union buffer)

__device__ __forceinline__ void fma4(float4& a, float x, const float4& w) {
    a.x = fmaf(x, w.x, a.x); a.y = fmaf(x, w.y, a.y);
    a.z = fmaf(x, w.z, a.z); a.w = fmaf(x, w.w, a.w);
}

// Write-through (agent-visible) scalar store: lowers to global_store with sc1
// -> bypasses/writes through the per-XCD L2 into the memory-side MALL, so no
// L2 writeback fence is needed for cross-XCD visibility.
__device__ __forceinline__ void store_agent(float* p, float v) {
    __hip_atomic_store(p, v, __ATOMIC_RELAXED, __HIP_MEMORY_SCOPE_AGENT);
}

// Manual grid barrier, NO cache-maintenance ops (the round-2 kernel spent
// ~50us in per-thread __threadfence L2 writeback/invalidate).
// Ordering: all handoff data was stored with sc1 (write-through). vmcnt(0)
// guarantees those stores are committed to the coherence point before the
// arrive; the spin load is agent-scope (sc1) so it polls MALL, not stale L2.
// All NBLOCKS blocks are co-resident by construction (128 blocks <= 256 CUs,
// 78.3KB LDS, 1 block/CU) so the spin cannot deadlock.
__device__ __forceinline__ void grid_barrier(unsigned int* ctr, unsigned int nb) {
    asm volatile("s_waitcnt vmcnt(0)" ::: "memory");
    __syncthreads();
    if (threadIdx.x == 0) {
        __hip_atomic_fetch_add(ctr, 1u, __ATOMIC_RELAXED, __HIP_MEMORY_SCOPE_AGENT);
        while (__hip_atomic_load(ctr, __ATOMIC_RELAXED, __HIP_MEMORY_SCOPE_AGENT) < nb) {
            __builtin_amdgcn_s_sleep(2);
        }
    }
    __syncthreads();
}

// Single fused kernel: 128 blocks x 256 threads, 2 manual grid barriers.
// Phase 1 (all 128 blocks):  f[h,n,e] = relu(Xs @ FC[h])        (old k1)
// Phase 2 (blocks 0..63):    hdn[h,n,m] = tanh([f,ROI]@W1+b1)   (old k2)
// Phase 3 (blocks 0..16):    scores -> softmax -> weighted sum  (old k34)
__global__ __launch_bounds__(256) void fused_all(
        const float* __restrict__ Xs,     const float* __restrict__ ROIs,
        const float* __restrict__ FC,     const float* __restrict__ W1,
        const float* __restrict__ b1,     const float* __restrict__ W2,
        const float* __restrict__ b2,     const float* __restrict__ conv_w,
        const float* __restrict__ conv_b, float* __restrict__ out,
        float* __restrict__ f,            float* __restrict__ hdn,
        unsigned int* __restrict__ ctrs) {
    const int b = blockIdx.x;
    const int t = threadIdx.x;
    __shared__ __align__(16) float sm[SMEM_FL];

    // ---------------- Phase 1: f = relu(Xs @ FC[h]) ----------------
    {
        const int et = b & 15, h = b >> 4;
        const int tw = t & 7, cgr = t >> 3;
        for (int i = t; i < NN * D; i += 256) {
            const int n = i >> 9, d = i & 511;
            sm[d * XPAD + n] = Xs[i];
        }
        __syncthreads();
        float4 acc[NN];
#pragma unroll
        for (int n = 0; n < NN; ++n) acc[n] = make_float4(0.f, 0.f, 0.f, 0.f);
        const float4* fc4 = (const float4*)(FC + (size_t)h * D * D) + et * 8 + tw;
#pragma unroll 4
        for (int i = 0; i < 16; ++i) {
            const int d = cgr + (i << 5);
            const float4 w = fc4[d << 7];            // [d][512/4] row stride 128
            const float* xr = sm + d * XPAD;
#pragma unroll
            for (int n4 = 0; n4 < 4; ++n4) {
                const float4 x = *(const float4*)(xr + (n4 << 2));
                fma4(acc[n4 * 4 + 0], x.x, w);
                fma4(acc[n4 * 4 + 1], x.y, w);
                fma4(acc[n4 * 4 + 2], x.z, w);
                fma4(acc[n4 * 4 + 3], x.w, w);
            }
            fma4(acc[16], xr[16], w);
        }
        __syncthreads();                 // xs_t reads done; reuse smem for reduction
        float* rr = sm + cgr * RSG + tw * 4;
#pragma unroll
        for (int n = 0; n < NN; ++n) *(float4*)(rr + n * RSN) = acc[n];
        __syncthreads();
        for (int i = t; i < NN * 32; i += 256) {
            const int n = i >> 5, e = i & 31;
            float s = 0.f;
#pragma unroll 8
            for (int g = 0; g < 32; ++g) s += sm[g * RSG + n * RSN + e];
            store_agent(&f[((h * NN + n) << 9) + (et << 5) + e], fmaxf(s, 0.f));
        }
    }
    grid_barrier(ctrs + 0, NBLOCKS);     // f committed to MALL, visible to all blocks

    // ---------------- Phase 2: hdn = tanh([f,ROI] @ W1 + b1) ----------------
    if (b < H * 8) {
        const int mt = b & 7, h = b >> 3;
        const int tw = t & 7, cgr = t >> 3;
        for (int i = t; i < NN * D; i += 256) {
            const int n = i >> 9, d = i & 511;
            sm[d * XPAD + n] = f[((size_t)(h * NN) << 9) + i];
        }
        if (t < NN * 3) {
            const int n = t / 3, cc = t % 3;
            sm[(D + cc) * XPAD + n] = ROIs[t];
        }
        __syncthreads();
        float4 acc[NN];
#pragma unroll
        for (int n = 0; n < NN; ++n) acc[n] = make_float4(0.f, 0.f, 0.f, 0.f);
        const float4* w4 = (const float4*)(W1 + (size_t)h * C1 * M) + mt * 8 + tw;
#pragma unroll 4
        for (int i = 0; i < 16; ++i) {
            const int c = cgr + (i << 5);
            const float4 w = w4[c << 6];             // [c][256/4] row stride 64
            const float* xr = sm + c * XPAD;
#pragma unroll
            for (int n4 = 0; n4 < 4; ++n4) {
                const float4 x = *(const float4*)(xr + (n4 << 2));
                fma4(acc[n4 * 4 + 0], x.x, w);
                fma4(acc[n4 * 4 + 1], x.y, w);
                fma4(acc[n4 * 4 + 2], x.z, w);
                fma4(acc[n4 * 4 + 3], x.w, w);
            }
            fma4(acc[16], xr[16], w);
        }
        if (cgr < 3) {                               // tail rows c = 512..514 (ROI)
            const int c = D + cgr;
            const float4 w = w4[c << 6];
            const float* xr = sm + c * XPAD;
#pragma unroll
            for (int n4 = 0; n4 < 4; ++n4) {
                const float4 x = *(const float4*)(xr + (n4 << 2));
                fma4(acc[n4 * 4 + 0], x.x, w);
                fma4(acc[n4 * 4 + 1], x.y, w);
                fma4(acc[n4 * 4 + 2], x.z, w);
                fma4(acc[n4 * 4 + 3], x.w, w);
            }
            fma4(acc[16], xr[16], w);
        }
        __syncthreads();
        float* rr = sm + cgr * RSG + tw * 4;
#pragma unroll
        for (int n = 0; n < NN; ++n) *(float4*)(rr + n * RSN) = acc[n];
        __syncthreads();
        for (int i = t; i < NN * 32; i += 256) {
            const int n = i >> 5, m = i & 31;
            float s = b1[h * M + (mt << 5) + m];
#pragma unroll 8
            for (int g = 0; g < 32; ++g) s += sm[g * RSG + n * RSN + m];
            store_agent(&hdn[(h * NN + n) * M + (mt << 5) + m], tanhf(s));
        }
    }
    grid_barrier(ctrs + 32, NBLOCKS);    // hdn committed to MALL, visible to all blocks

    // ---------------- Phase 3: scores -> softmax -> output ----------------
    if (b < NN) {
        const int k = b;
        float* swk = sm;                        // [H][M+4], row stride 260 (16B-aligned)
        float* sa  = sm + H * (M + 4);          // [H][NN]
        float* cwv = sm + H * (M + 4) + H * NN; // [H]
        for (int i = t; i < H * M; i += 256) {
            const int h = i >> 8, m = i & 255;
            swk[h * (M + 4) + m] = W2[(size_t)(h * M + m) * NN + k];
        }
        if (t < H) cwv[t] = conv_w[t];
        __syncthreads();
        if (t < H * NN) {
            const int h = t / NN, n = t % NN;
            const float4* a4 = (const float4*)(hdn + (h * NN + n) * M);
            const float4* w4 = (const float4*)(swk + h * (M + 4));
            float acc = b2[h * NN + k];
#pragma unroll 8
            for (int m4 = 0; m4 < M / 4; ++m4) {
                const float4 av = a4[m4];
                const float4 wv = w4[m4];
                acc = fmaf(av.x, wv.x, acc); acc = fmaf(av.y, wv.y, acc);
                acc = fmaf(av.z, wv.z, acc); acc = fmaf(av.w, wv.w, acc);
            }
            sa[h * NN + n] = acc;
        }
        __syncthreads();
        if (t < H) {
            float mx = -1e30f;
#pragma unroll
            for (int n = 0; n < NN; ++n) mx = fmaxf(mx, sa[t * NN + n]);
            float e[NN];
            float s = 0.f;
#pragma unroll
            for (int n = 0; n < NN; ++n) { e[n] = __expf(sa[t * NN + n] - mx); s += e[n]; }
            const float inv = 1.f / s;
#pragma unroll
            for (int n = 0; n < NN; ++n) sa[t * NN + n] = e[n] * inv;
        }
        __syncthreads();
        const float cb = conv_b[0];
        float acc0 = 0.f, acc1 = 0.f;
        for (int h = 0; h < H; ++h) {
            float w0 = 0.f, w1 = 0.f;
#pragma unroll
            for (int n = 0; n < NN; ++n) {
                const float a = sa[h * NN + n];
                const float* fr = f + (size_t)((h * NN + n) << 9);
                w0 = fmaf(a, fr[t], w0);
                w1 = fmaf(a, fr[t + 256], w1);
            }
            acc0 = fmaf(cwv[h], w0, acc0);
            acc1 = fmaf(cwv[h], w1, acc1);
        }
        out[(k << 9) + t]       = fmaxf(acc0 + cb, 0.f) + Xs[(k << 9) + t];
        out[(k << 9) + t + 256] = fmaxf(acc1 + cb, 0.f) + Xs[(k << 9) + t + 256];
        if (k == 0 && t < NN * 3) out[NN * D + t] = ROIs[t];
    }
}

extern "C" void kernel_launch(void* const* d_in, const int* in_sizes, int n_in,
                              void* d_out, int out_size, void* d_ws, size_t ws_size,
                              hipStream_t stream) {
    const float* Xs     = (const float*)d_in[0];
    const float* ROIs   = (const float*)d_in[1];
    // d_in[2] = adj, unused
    const float* FC     = (const float*)d_in[3];
    const float* W1     = (const float*)d_in[4];
    const float* b1     = (const float*)d_in[5];
    const float* W2     = (const float*)d_in[6];
    const float* b2     = (const float*)d_in[7];
    const float* conv_w = (const float*)d_in[8];
    const float* conv_b = (const float*)d_in[9];
    float* outp = (float*)d_out;

    float* fbuf   = (float*)d_ws;              // H*NN*D = 69632 floats
    float* hdnbuf = fbuf + H * NN * D;         // H*NN*M = 34816 floats

    // Barrier counters: far from f/hdn, zeroed each launch (stream-ordered,
    // graph-capturable). Two counters, 128B apart.
    unsigned int* ctrs = (unsigned int*)((char*)d_ws + (1u << 20));
    hipMemsetAsync(ctrs, 0, 256, stream);

    fused_all<<<NBLOCKS, 256, 0, stream>>>(Xs, ROIs, FC, W1, b1, W2, b2,
                                           conv_w, conv_b, outp, fbuf, hdnbuf,
                                           ctrs);
}

// Round 4
// 108.554 us; speedup vs baseline: 1.3495x; 1.0574x over previous
//
#include <hip/hip_runtime.h>

#define NN 17    // nodes
#define D  512   // feature dim
#define H  8     // heads
#define C1 515   // D + 3
#define M  256   // hidden

#define NBLOCKS 128                          // = H*16 (phase-1 grid); <= 256 CUs -> all co-resident

#define XPAD 20                              // [d][n] row stride (17 + pad)
#define RSN  36                              // reduction row: 32 e + pad
#define RSG  (NN * RSN)                      // 612 floats per group
#define SMEM_FL (32 * RSG)                   // 19584 floats = 78.3 KB (union buffer)

// Counter layout (uint index into ctrs; 32 uints = 128 B apart -> own cacheline):
//   ctr1[h]  at  h*32        (h=0..7): 16 arrivals each (phase-1 blocks of head h)
//   ctr2h[h] at  256 + h*32  (h=0..7): 8 arrivals each (phase-2 blocks of head h)
//   ctr2f    at  512        : 8 arrivals (last arriver of each ctr2h)
#define CTR1(h)  ((h) * 32)
#define CTR2H(h) (256 + (h) * 32)
#define CTR2F    512

__device__ __forceinline__ void fma4(float4& a, float x, const float4& w) {
    a.x = fmaf(x, w.x, a.x); a.y = fmaf(x, w.y, a.y);
    a.z = fmaf(x, w.z, a.z); a.w = fmaf(x, w.w, a.w);
}

// Write-through (agent-visible) scalar store: global_store with sc1 -> commits
// to MALL (memory-side, coherent across XCDs); no L2 flush needed.
__device__ __forceinline__ void store_agent(float* p, float v) {
    __hip_atomic_store(p, v, __ATOMIC_RELAXED, __HIP_MEMORY_SCOPE_AGENT);
}

__device__ __forceinline__ unsigned ctr_add(unsigned* c) {
    return __hip_atomic_fetch_add(c, 1u, __ATOMIC_RELAXED, __HIP_MEMORY_SCOPE_AGENT);
}

// Arrive: all 4 waves drain their own vmem (sc1 data stores committed), block
// barrier, then one agent-scope RMW by thread 0.
__device__ __forceinline__ void arrive(unsigned* c) {
    asm volatile("s_waitcnt vmcnt(0)" ::: "memory");
    __syncthreads();
    if (threadIdx.x == 0) ctr_add(c);
}

// Wait: thread 0 polls at agent scope (MALL), others park at the barrier.
__device__ __forceinline__ void wait_ge(unsigned* c, unsigned nb) {
    if (threadIdx.x == 0) {
        while (__hip_atomic_load(c, __ATOMIC_RELAXED, __HIP_MEMORY_SCOPE_AGENT) < nb) {
            __builtin_amdgcn_s_sleep(1);
        }
    }
    __syncthreads();
}

// Single fused kernel: 128 blocks x 256 threads, dependency-pruned tree barriers.
// Phase 1 (all 128 blocks, b=(h,et)):  f[h,n,e] = relu(Xs @ FC[h])
// Phase 2 (blocks 0..63,  b=(h,mt)):   hdn[h,n,m] = tanh([f,ROI]@W1+b1)
//   - waits only on ctr1[h] (the 16 producers of f[h]), W1 loads hoisted above the spin
// Phase 3 (blocks 0..16,  b=k):        scores -> softmax -> weighted sum
//   - waits on ctr2f (all 64 phase-2 blocks, tree), W2 staging hoisted above the spin
__global__ __launch_bounds__(256) void fused_all(
        const float* __restrict__ Xs,     const float* __restrict__ ROIs,
        const float* __restrict__ FC,     const float* __restrict__ W1,
        const float* __restrict__ b1,     const float* __restrict__ W2,
        const float* __restrict__ b2,     const float* __restrict__ conv_w,
        const float* __restrict__ conv_b, float* __restrict__ out,
        float* __restrict__ f,            float* __restrict__ hdn,
        unsigned int* __restrict__ ctrs) {
    const int b = blockIdx.x;
    const int t = threadIdx.x;
    const int tw = t & 7, cgr = t >> 3;
    __shared__ __align__(16) float sm[SMEM_FL];

    // ---------------- Phase 1: f = relu(Xs @ FC[h1]) ----------------
    {
        const int et = b & 15, h1 = b >> 4;
        // Hoist all 16 FC float4 loads: latency hides under Xs staging.
        float4 wreg[16];
        const float4* fc4 = (const float4*)(FC + (size_t)h1 * D * D) + et * 8 + tw;
#pragma unroll
        for (int i = 0; i < 16; ++i) wreg[i] = fc4[(cgr + (i << 5)) << 7];
        for (int i = t; i < NN * D; i += 256) {
            const int n = i >> 9, d = i & 511;
            sm[d * XPAD + n] = Xs[i];
        }
        __syncthreads();
        float4 acc[NN];
#pragma unroll
        for (int n = 0; n < NN; ++n) acc[n] = make_float4(0.f, 0.f, 0.f, 0.f);
#pragma unroll
        for (int i = 0; i < 16; ++i) {
            const float4 w = wreg[i];
            const float* xr = sm + (cgr + (i << 5)) * XPAD;
#pragma unroll
            for (int n4 = 0; n4 < 4; ++n4) {
                const float4 x = *(const float4*)(xr + (n4 << 2));
                fma4(acc[n4 * 4 + 0], x.x, w);
                fma4(acc[n4 * 4 + 1], x.y, w);
                fma4(acc[n4 * 4 + 2], x.z, w);
                fma4(acc[n4 * 4 + 3], x.w, w);
            }
            fma4(acc[16], xr[16], w);
        }
        __syncthreads();                 // xs_t reads done; reuse smem for reduction
        float* rr = sm + cgr * RSG + tw * 4;
#pragma unroll
        for (int n = 0; n < NN; ++n) *(float4*)(rr + n * RSN) = acc[n];
        __syncthreads();
        for (int i = t; i < NN * 32; i += 256) {
            const int n = i >> 5, e = i & 31;
            float s = 0.f;
#pragma unroll 8
            for (int g = 0; g < 32; ++g) s += sm[g * RSG + n * RSN + e];
            store_agent(&f[((h1 * NN + n) << 9) + (et << 5) + e], fmaxf(s, 0.f));
        }
        arrive(ctrs + CTR1(h1));         // f[h1] slice committed
    }
    if (b >= H * 8) return;              // blocks 64..127: done (no rendezvous)

    // ---------------- Phase 2: hdn = tanh([f,ROI] @ W1 + b1) ----------------
    {
        const int mt = b & 7, h2 = b >> 3;
        // Hoist all 17 W1 float4 loads ABOVE the spin: latency hides under wait.
        float4 w1r[17];
        const float4* w4 = (const float4*)(W1 + (size_t)h2 * C1 * M) + mt * 8 + tw;
#pragma unroll
        for (int i = 0; i < 16; ++i) w1r[i] = w4[(cgr + (i << 5)) << 6];
        w1r[16] = (cgr < 3) ? w4[(D + cgr) << 6] : make_float4(0.f, 0.f, 0.f, 0.f);
        __builtin_amdgcn_sched_barrier(0);   // keep loads issued before the spin
        wait_ge(ctrs + CTR1(h2), 16);        // only the 16 producers of f[h2]
        for (int i = t; i < NN * D; i += 256) {
            const int n = i >> 9, d = i & 511;
            sm[d * XPAD + n] = f[((size_t)(h2 * NN) << 9) + i];
        }
        if (t < NN * 3) {
            const int n = t / 3, cc = t % 3;
            sm[(D + cc) * XPAD + n] = ROIs[t];
        }
        __syncthreads();
        float4 acc[NN];
#pragma unroll
        for (int n = 0; n < NN; ++n) acc[n] = make_float4(0.f, 0.f, 0.f, 0.f);
#pragma unroll
        for (int i = 0; i < 16; ++i) {
            const float4 w = w1r[i];
            const float* xr = sm + (cgr + (i << 5)) * XPAD;
#pragma unroll
            for (int n4 = 0; n4 < 4; ++n4) {
                const float4 x = *(const float4*)(xr + (n4 << 2));
                fma4(acc[n4 * 4 + 0], x.x, w);
                fma4(acc[n4 * 4 + 1], x.y, w);
                fma4(acc[n4 * 4 + 2], x.z, w);
                fma4(acc[n4 * 4 + 3], x.w, w);
            }
            fma4(acc[16], xr[16], w);
        }
        if (cgr < 3) {                               // tail rows c = 512..514 (ROI)
            const float4 w = w1r[16];
            const float* xr = sm + (D + cgr) * XPAD;
#pragma unroll
            for (int n4 = 0; n4 < 4; ++n4) {
                const float4 x = *(const float4*)(xr + (n4 << 2));
                fma4(acc[n4 * 4 + 0], x.x, w);
                fma4(acc[n4 * 4 + 1], x.y, w);
                fma4(acc[n4 * 4 + 2], x.z, w);
                fma4(acc[n4 * 4 + 3], x.w, w);
            }
            fma4(acc[16], xr[16], w);
        }
        __syncthreads();
        float* rr = sm + cgr * RSG + tw * 4;
#pragma unroll
        for (int n = 0; n < NN; ++n) *(float4*)(rr + n * RSN) = acc[n];
        __syncthreads();
        for (int i = t; i < NN * 32; i += 256) {
            const int n = i >> 5, m = i & 31;
            float s = b1[h2 * M + (mt << 5) + m];
#pragma unroll 8
            for (int g = 0; g < 32; ++g) s += sm[g * RSG + n * RSN + m];
            store_agent(&hdn[(h2 * NN + n) * M + (mt << 5) + m], tanhf(s));
        }
        // Tree arrive: 8 per ctr2h line; 8th arriver bumps ctr2f.
        asm volatile("s_waitcnt vmcnt(0)" ::: "memory");
        __syncthreads();
        if (t == 0) {
            if (ctr_add(ctrs + CTR2H(h2)) == 7u) ctr_add(ctrs + CTR2F);
        }
    }
    if (b >= NN) return;                 // blocks 17..63: done

    // ---------------- Phase 3: scores -> softmax -> output ----------------
    {
        const int k = b;
        float* swk = sm;                        // [H][M+4], row stride 260 (16B-aligned)
        float* sa  = sm + H * (M + 4);          // [H][NN]
        float* cwv = sm + H * (M + 4) + H * NN; // [H]
        // Stage W2 column k + conv_w ABOVE the spin (independent of hdn).
        for (int i = t; i < H * M; i += 256) {
            const int h = i >> 8, m = i & 255;
            swk[h * (M + 4) + m] = W2[(size_t)(h * M + m) * NN + k];
        }
        if (t < H) cwv[t] = conv_w[t];
        __builtin_amdgcn_sched_barrier(0);
        wait_ge(ctrs + CTR2F, 8);               // all 64 phase-2 blocks done
        if (t < H * NN) {
            const int h = t / NN, n = t % NN;
            const float4* a4 = (const float4*)(hdn + (h * NN + n) * M);
            const float4* w4 = (const float4*)(swk + h * (M + 4));
            float acc = b2[h * NN + k];
#pragma unroll 8
            for (int m4 = 0; m4 < M / 4; ++m4) {
                const float4 av = a4[m4];
                const float4 wv = w4[m4];
                acc = fmaf(av.x, wv.x, acc); acc = fmaf(av.y, wv.y, acc);
                acc = fmaf(av.z, wv.z, acc); acc = fmaf(av.w, wv.w, acc);
            }
            sa[h * NN + n] = acc;
        }
        __syncthreads();
        if (t < H) {
            float mx = -1e30f;
#pragma unroll
            for (int n = 0; n < NN; ++n) mx = fmaxf(mx, sa[t * NN + n]);
            float e[NN];
            float s = 0.f;
#pragma unroll
            for (int n = 0; n < NN; ++n) { e[n] = __expf(sa[t * NN + n] - mx); s += e[n]; }
            const float inv = 1.f / s;
#pragma unroll
            for (int n = 0; n < NN; ++n) sa[t * NN + n] = e[n] * inv;
        }
        __syncthreads();
        const float cb = conv_b[0];
        float acc0 = 0.f, acc1 = 0.f;
        for (int h = 0; h < H; ++h) {
            float w0 = 0.f, w1 = 0.f;
#pragma unroll
            for (int n = 0; n < NN; ++n) {
                const float a = sa[h * NN + n];
                const float* fr = f + (size_t)((h * NN + n) << 9);
                w0 = fmaf(a, fr[t], w0);
                w1 = fmaf(a, fr[t + 256], w1);
            }
            acc0 = fmaf(cwv[h], w0, acc0);
            acc1 = fmaf(cwv[h], w1, acc1);
        }
        out[(k << 9) + t]       = fmaxf(acc0 + cb, 0.f) + Xs[(k << 9) + t];
        out[(k << 9) + t + 256] = fmaxf(acc1 + cb, 0.f) + Xs[(k << 9) + t + 256];
        if (k == 0 && t < NN * 3) out[NN * D + t] = ROIs[t];
    }
}

extern "C" void kernel_launch(void* const* d_in, const int* in_sizes, int n_in,
                              void* d_out, int out_size, void* d_ws, size_t ws_size,
                              hipStream_t stream) {
    const float* Xs     = (const float*)d_in[0];
    const float* ROIs   = (const float*)d_in[1];
    // d_in[2] = adj, unused
    const float* FC     = (const float*)d_in[3];
    const float* W1     = (const float*)d_in[4];
    const float* b1     = (const float*)d_in[5];
    const float* W2     = (const float*)d_in[6];
    const float* b2     = (const float*)d_in[7];
    const float* conv_w = (const float*)d_in[8];
    const float* conv_b = (const float*)d_in[9];
    float* outp = (float*)d_out;

    float* fbuf   = (float*)d_ws;              // H*NN*D = 69632 floats
    float* hdnbuf = fbuf + H * NN * D;         // H*NN*M = 34816 floats

    // Counters live past the data buffers; the harness poisons d_ws every
    // iteration, so they MUST be re-zeroed each launch (stream-ordered,
    // graph-capturable memset).
    unsigned int* ctrs = (unsigned int*)((char*)d_ws + (1u << 20));
    hipMemsetAsync(ctrs, 0, (512 + 32) * sizeof(unsigned int), stream);

    fused_all<<<NBLOCKS, 256, 0, stream>>>(Xs, ROIs, FC, W1, b1, W2, b2,
                                           conv_w, conv_b, outp, fbuf, hdnbuf,
                                           ctrs);
}